// Round 2
// baseline (881.219 us; speedup 1.0000x reference)
//
#include <hip/hip_runtime.h>

#define T_DIM 2048
#define H_DIM 16
#define D_DIM 128
#define TC 32      // timesteps staged per chunk
#define NCG 4      // column groups per (b,h) pair
#define CPB 32     // columns per block

__device__ __forceinline__ float blo(unsigned u){ return __uint_as_float(u << 16); }
__device__ __forceinline__ float bhi(unsigned u){ return __uint_as_float(u & 0xffff0000u); }
__device__ __forceinline__ unsigned f2bf(float x){   // fp32 -> bf16 (RNE), finite inputs
  unsigned u = __float_as_uint(x);
  return (u + 0x7fffu + ((u >> 16) & 1u)) >> 16;
}
__device__ __forceinline__ uint2 pack4(float4 v){
  uint2 r;
  r.x = f2bf(v.x) | (f2bf(v.y) << 16);
  r.y = f2bf(v.z) | (f2bf(v.w) << 16);
  return r;
}
// sum across the 16 lanes of a DPP row (our column-group) via row_ror rotations
__device__ __forceinline__ float row_sum16(float x){
  x += __int_as_float(__builtin_amdgcn_update_dpp(0, __float_as_int(x), 0x121, 0xf, 0xf, true));
  x += __int_as_float(__builtin_amdgcn_update_dpp(0, __float_as_int(x), 0x122, 0xf, 0xf, true));
  x += __int_as_float(__builtin_amdgcn_update_dpp(0, __float_as_int(x), 0x124, 0xf, 0xf, true));
  x += __int_as_float(__builtin_amdgcn_update_dpp(0, __float_as_int(x), 0x128, 0xf, 0xf, true));
  return x;
}

// grid = 64 pairs * 4 colgroups = 256 blocks; block = 256 threads
// thread: cc = tid>>4 (owns 2 cols), rc = tid&15 (owns 8 rows) -> 16 M elems in regs
__global__ __launch_bounds__(256, 1)
void deltanet_kernel(const float* __restrict__ qg,
                     const float* __restrict__ kg,
                     const float* __restrict__ vg,
                     const float* __restrict__ fg,
                     const float* __restrict__ gg,
                     float* __restrict__ out)
{
  __shared__ unsigned short qs [TC][D_DIM];   // bf16 staged
  __shared__ unsigned short fs [TC][D_DIM];   // bf16 staged
  __shared__ unsigned short kgs[TC][D_DIM];   // k*g, bf16
  __shared__ unsigned short vgs[TC][D_DIM];   // v*g, bf16
  __shared__ float obuf[TC][CPB];

  const int tid  = threadIdx.x;
  const int blk  = blockIdx.x;
  const int pair = blk >> 2;        // 0..63 = b*16 + h
  const int cg   = blk & 3;
  const int bb   = pair >> 4;
  const int hh   = pair & 15;
  const int cc   = tid >> 4;        // 0..15
  const int rc   = tid & 15;        // 0..15
  const int c0   = cg * CPB + cc * 2;
  const int r0   = rc * 8;

  const size_t base0 = ((size_t)bb * T_DIM * H_DIM + hh) * (size_t)D_DIM;
  const float* qp = qg + base0;
  const float* kp = kg + base0;
  const float* vp = vg + base0;
  const float* fp = fg + base0;
  const float* gp = gg + base0;
  float*       op = out + base0;

  float M0[8], M1[8];
  #pragma unroll
  for (int j = 0; j < 8; ++j) { M0[j] = 0.f; M1[j] = 0.f; }

  for (int t0 = 0; t0 < T_DIM; t0 += TC) {
    // ---------------- stage chunk: global (fp32) -> LDS (bf16) ----------------
    #pragma unroll
    for (int it = 0; it < 4; ++it) {
      const int flat = (it * 256 + tid) * 4;          // float index 0..4095
      const int s = flat >> 7;
      const int r = flat & 127;
      const size_t go = (size_t)(t0 + s) * (H_DIM * D_DIM) + r;
      float4 qv = *(const float4*)(qp + go);
      float4 fv = *(const float4*)(fp + go);
      *(uint2*)&qs[s][r] = pack4(qv);
      *(uint2*)&fs[s][r] = pack4(fv);
      float4 kv = *(const float4*)(kp + go);
      float4 gv = *(const float4*)(gp + go);
      float4 vv = *(const float4*)(vp + go);
      float4 kgv = make_float4(kv.x*gv.x, kv.y*gv.y, kv.z*gv.z, kv.w*gv.w);
      float4 vgv = make_float4(vv.x*gv.x, vv.y*gv.y, vv.z*gv.z, vv.w*gv.w);
      *(uint2*)&kgs[s][r] = pack4(kgv);
      *(uint2*)&vgs[s][r] = pack4(vgv);
    }
    __syncthreads();

    // ---------------- recurrence over the chunk ----------------
    #pragma unroll 2
    for (int s = 0; s < TC; ++s) {
      const unsigned fcp = *(const unsigned*)&fs [s][c0];   // 2 col f's
      const unsigned vcp = *(const unsigned*)&vgs[s][c0];   // 2 col vg's
      const float fc0 = blo(fcp), fc1 = bhi(fcp);
      const float vc0 = blo(vcp), vc1 = bhi(vcp);
      uint4 q4 = *(const uint4*)&qs [s][r0];  // 8 rows of q  (bf16)
      uint4 f4 = *(const uint4*)&fs [s][r0];  // 8 rows of f
      uint4 k4 = *(const uint4*)&kgs[s][r0];  // 8 rows of k*g
      const unsigned* qa = (const unsigned*)&q4;
      const unsigned* fa = (const unsigned*)&f4;
      const unsigned* kk = (const unsigned*)&k4;
      float po0 = 0.f, po1 = 0.f;
      #pragma unroll
      for (int w = 0; w < 4; ++w) {
        float qr = blo(qa[w]), fr = blo(fa[w]), kr = blo(kk[w]);
        // f in [0,1] -> f_r*f_c <= 1.0 always, so clip == fmax(.,0.8)
        float fo0 = fmaxf(fr * fc0, 0.8f);
        float fo1 = fmaxf(fr * fc1, 0.8f);
        M0[2*w]   = fmaf(M0[2*w],   fo0, kr * vc0);
        M1[2*w]   = fmaf(M1[2*w],   fo1, kr * vc1);
        po0 = fmaf(qr, M0[2*w],   po0);
        po1 = fmaf(qr, M1[2*w],   po1);
        qr = bhi(qa[w]); fr = bhi(fa[w]); kr = bhi(kk[w]);
        fo0 = fmaxf(fr * fc0, 0.8f);
        fo1 = fmaxf(fr * fc1, 0.8f);
        M0[2*w+1] = fmaf(M0[2*w+1], fo0, kr * vc0);
        M1[2*w+1] = fmaf(M1[2*w+1], fo1, kr * vc1);
        po0 = fmaf(qr, M0[2*w+1], po0);
        po1 = fmaf(qr, M1[2*w+1], po1);
      }
      po0 = row_sum16(po0);
      po1 = row_sum16(po1);
      if (rc == 0) {
        obuf[s][cc*2]   = po0;
        obuf[s][cc*2+1] = po1;
      }
    }
    __syncthreads();

    // ---------------- flush chunk outputs (fp32) ----------------
    {
      const int s = tid >> 3;            // 0..31
      const int c = (tid & 7) * 4;       // 0..28
      float4 ov = *(const float4*)&obuf[s][c];
      *(float4*)(op + (size_t)(t0 + s) * (H_DIM * D_DIM) + cg * CPB + c) = ov;
    }
    // no barrier needed: next stage writes qs/fs/kgs/vgs (reads done pre-barrier),
    // flush reads obuf (next writes are after the pre-compute barrier)
  }
}

extern "C" void kernel_launch(void* const* d_in, const int* in_sizes, int n_in,
                              void* d_out, int out_size, void* d_ws, size_t ws_size,
                              hipStream_t stream) {
  const float* q = (const float*)d_in[0];
  const float* k = (const float*)d_in[1];
  const float* v = (const float*)d_in[2];
  const float* f = (const float*)d_in[3];
  const float* g = (const float*)d_in[4];
  float* out = (float*)d_out;
  deltanet_kernel<<<dim3(64 * NCG), dim3(256), 0, stream>>>(q, k, v, f, g, out);
}

// Round 3
// 832.007 us; speedup vs baseline: 1.0591x; 1.0591x over previous
//
#include <hip/hip_runtime.h>

#define T_DIM 2048
#define H_DIM 16
#define D_DIM 128
#define TC 32      // timesteps staged per chunk
#define NCG 4      // column groups per (b,h) pair
#define CPB 32     // columns per block

typedef float v2f __attribute__((ext_vector_type(2)));

__device__ __forceinline__ float blo(unsigned u){ return __uint_as_float(u << 16); }
__device__ __forceinline__ float bhi(unsigned u){ return __uint_as_float(u & 0xffff0000u); }
__device__ __forceinline__ unsigned f2bf(float x){   // fp32 -> bf16 (RNE), finite inputs
  unsigned u = __float_as_uint(x);
  return (u + 0x7fffu + ((u >> 16) & 1u)) >> 16;
}
__device__ __forceinline__ uint2 pack4(float4 v){
  uint2 r;
  r.x = f2bf(v.x) | (f2bf(v.y) << 16);
  r.y = f2bf(v.z) | (f2bf(v.w) << 16);
  return r;
}
// bf16 pair (rows 2j, 2j+1) -> float2
__device__ __forceinline__ v2f up2(unsigned u){
  v2f r; r.x = __uint_as_float(u << 16); r.y = __uint_as_float(u & 0xffff0000u); return r;
}
#if defined(__has_builtin) && __has_builtin(__builtin_elementwise_fma)
__device__ __forceinline__ v2f v2fma(v2f a, v2f b, v2f c){ return __builtin_elementwise_fma(a, b, c); }
#else
__device__ __forceinline__ v2f v2fma(v2f a, v2f b, v2f c){ v2f r; r.x=fmaf(a.x,b.x,c.x); r.y=fmaf(a.y,b.y,c.y); return r; }
#endif
// sum across the 16 lanes of a DPP row (our column-group) via row_ror rotations
__device__ __forceinline__ float row_sum16(float x){
  x += __int_as_float(__builtin_amdgcn_update_dpp(0, __float_as_int(x), 0x121, 0xf, 0xf, true));
  x += __int_as_float(__builtin_amdgcn_update_dpp(0, __float_as_int(x), 0x122, 0xf, 0xf, true));
  x += __int_as_float(__builtin_amdgcn_update_dpp(0, __float_as_int(x), 0x124, 0xf, 0xf, true));
  x += __int_as_float(__builtin_amdgcn_update_dpp(0, __float_as_int(x), 0x128, 0xf, 0xf, true));
  return x;
}

// grid = 64 pairs * 4 colgroups = 256 blocks; block = 256 threads
// thread: cc = tid>>4 (owns 2 cols), rc = tid&15 (owns 8 rows) -> 16 M elems
// M held as float2 row-pairs so the update runs on v_pk_fma_f32 / v_pk_mul_f32
__global__ __launch_bounds__(256, 1)
void deltanet_kernel(const float* __restrict__ qg,
                     const float* __restrict__ kg,
                     const float* __restrict__ vg,
                     const float* __restrict__ fg,
                     const float* __restrict__ gg,
                     float* __restrict__ out)
{
  __shared__ unsigned short qs [TC][D_DIM];   // bf16 staged
  __shared__ unsigned short fs [TC][D_DIM];   // bf16 staged
  __shared__ unsigned short kgs[TC][D_DIM];   // k*g, bf16
  __shared__ unsigned short vgs[TC][D_DIM];   // v*g, bf16
  __shared__ float obuf[TC][CPB];

  const int tid  = threadIdx.x;
  const int blk  = blockIdx.x;
  const int pair = blk >> 2;        // 0..63 = b*16 + h
  const int cg   = blk & 3;
  const int bb   = pair >> 4;
  const int hh   = pair & 15;
  const int cc   = tid >> 4;        // 0..15
  const int rc   = tid & 15;        // 0..15
  const int c0   = cg * CPB + cc * 2;
  const int r0   = rc * 8;

  const size_t base0 = ((size_t)bb * T_DIM * H_DIM + hh) * (size_t)D_DIM;
  const float* qp = qg + base0;
  const float* kp = kg + base0;
  const float* vp = vg + base0;
  const float* fp = fg + base0;
  const float* gp = gg + base0;
  float*       op = out + base0;

  v2f M0[4], M1[4];                 // [row-pair] x {col0, col1}
  #pragma unroll
  for (int j = 0; j < 4; ++j) { M0[j] = (v2f){0.f,0.f}; M1[j] = (v2f){0.f,0.f}; }

  for (int t0 = 0; t0 < T_DIM; t0 += TC) {
    // ---------------- stage chunk: global (fp32) -> LDS (bf16) ----------------
    #pragma unroll
    for (int it = 0; it < 4; ++it) {
      const int flat = (it * 256 + tid) * 4;          // float index 0..4095
      const int s = flat >> 7;
      const int r = flat & 127;
      const size_t go = (size_t)(t0 + s) * (H_DIM * D_DIM) + r;
      float4 qv = *(const float4*)(qp + go);
      float4 fv = *(const float4*)(fp + go);
      *(uint2*)&qs[s][r] = pack4(qv);
      *(uint2*)&fs[s][r] = pack4(fv);
      float4 kv = *(const float4*)(kp + go);
      float4 gv = *(const float4*)(gp + go);
      float4 vv = *(const float4*)(vp + go);
      float4 kgv = make_float4(kv.x*gv.x, kv.y*gv.y, kv.z*gv.z, kv.w*gv.w);
      float4 vgv = make_float4(vv.x*gv.x, vv.y*gv.y, vv.z*gv.z, vv.w*gv.w);
      *(uint2*)&kgs[s][r] = pack4(kgv);
      *(uint2*)&vgs[s][r] = pack4(vgv);
    }
    __syncthreads();

    // ---------------- recurrence over the chunk (software-pipelined) ----------
    uint4 q4 = *(const uint4*)&qs [0][r0];
    uint4 f4 = *(const uint4*)&fs [0][r0];
    uint4 k4 = *(const uint4*)&kgs[0][r0];
    unsigned fcp = *(const unsigned*)&fs [0][c0];
    unsigned vcp = *(const unsigned*)&vgs[0][c0];

    #pragma unroll 4
    for (int s = 0; s < TC; ++s) {
      const uint4 q4c = q4, f4c = f4, k4c = k4;
      const unsigned fcpc = fcp, vcpc = vcp;
      if (s + 1 < TC) {                       // prefetch next step
        q4  = *(const uint4*)&qs [s+1][r0];
        f4  = *(const uint4*)&fs [s+1][r0];
        k4  = *(const uint4*)&kgs[s+1][r0];
        fcp = *(const unsigned*)&fs [s+1][c0];
        vcp = *(const unsigned*)&vgs[s+1][c0];
      }
      const float fc0 = blo(fcpc), fc1 = bhi(fcpc);
      const float vc0 = blo(vcpc), vc1 = bhi(vcpc);
      const v2f fcv0 = (v2f){fc0, fc0}, fcv1 = (v2f){fc1, fc1};
      const v2f vcv0 = (v2f){vc0, vc0}, vcv1 = (v2f){vc1, vc1};
      const unsigned* qa = (const unsigned*)&q4c;
      const unsigned* fa = (const unsigned*)&f4c;
      const unsigned* kk = (const unsigned*)&k4c;
      v2f po0 = (v2f){0.f,0.f}, po1 = (v2f){0.f,0.f};
      #pragma unroll
      for (int j = 0; j < 4; ++j) {           // 4 row-pairs
        const v2f qr = up2(qa[j]);
        const v2f fr = up2(fa[j]);
        const v2f kr = up2(kk[j]);
        v2f t0 = fr * fcv0;                   // v_pk_mul_f32
        v2f t1 = fr * fcv1;
        t0.x = fmaxf(t0.x, 0.8f); t0.y = fmaxf(t0.y, 0.8f);   // clip == fmax (f in [0,1])
        t1.x = fmaxf(t1.x, 0.8f); t1.y = fmaxf(t1.y, 0.8f);
        M0[j] = v2fma(M0[j], t0, kr * vcv0);  // v_pk_fma + v_pk_mul
        M1[j] = v2fma(M1[j], t1, kr * vcv1);
        po0 = v2fma(qr, M0[j], po0);
        po1 = v2fma(qr, M1[j], po1);
      }
      float p0 = po0.x + po0.y;
      float p1 = po1.x + po1.y;
      p0 = row_sum16(p0);
      p1 = row_sum16(p1);
      if (rc == 0) {
        obuf[s][cc*2]   = p0;
        obuf[s][cc*2+1] = p1;
      }
    }
    __syncthreads();

    // ---------------- flush chunk outputs (fp32) ----------------
    {
      const int s = tid >> 3;            // 0..31
      const int c = (tid & 7) * 4;       // 0..28
      float4 ov = *(const float4*)&obuf[s][c];
      *(float4*)(op + (size_t)(t0 + s) * (H_DIM * D_DIM) + cg * CPB + c) = ov;
    }
    // barrier-safety: flush(i) reads obuf before B1(i+1); compute(i+1) writes obuf
    // only after B1(i+1); staging(i+1) writes qs/fs/... which compute(i) finished
    // reading before B2(i). No extra barrier needed.
  }
}

extern "C" void kernel_launch(void* const* d_in, const int* in_sizes, int n_in,
                              void* d_out, int out_size, void* d_ws, size_t ws_size,
                              hipStream_t stream) {
  const float* q = (const float*)d_in[0];
  const float* k = (const float*)d_in[1];
  const float* v = (const float*)d_in[2];
  const float* f = (const float*)d_in[3];
  const float* g = (const float*)d_in[4];
  float* out = (float*)d_out;
  deltanet_kernel<<<dim3(64 * NCG), dim3(256), 0, stream>>>(q, k, v, f, g, out);
}